// Round 6
// baseline (322.365 us; speedup 1.0000x reference)
//
#include <hip/hip_runtime.h>
#include <cstdint>
#include <cstddef>

#define NTOK 8192      // B*S
#define SLEN 2048
#define DM   768
#define NH   12
#define DKH  64

typedef __attribute__((ext_vector_type(8))) short bf16x8;
typedef __attribute__((ext_vector_type(4))) float f32x4;

__device__ __forceinline__ float b2f(unsigned short u) {
  return __uint_as_float(((unsigned)u) << 16);
}
__device__ __forceinline__ unsigned short f2b(float f) {
  unsigned u = __float_as_uint(f);
  u += 0x7fffu + ((u >> 16) & 1u);   // RNE (no NaN inputs here)
  return (unsigned short)(u >> 16);
}
__device__ __forceinline__ unsigned cvtpk(float lo, float hi) {
  unsigned r;
  asm("v_cvt_pk_bf16_f32 %0, %1, %2" : "=v"(r) : "v"(lo), "v"(hi));
  return r;
}

__device__ __forceinline__ void gld16(const void* g, void* l) {
  __builtin_amdgcn_global_load_lds(
      (const __attribute__((address_space(1))) void*)g,
      (__attribute__((address_space(3))) void*)l, 16, 0, 0);
}

// ---------------- fp32 -> bf16 cast ----------------
__global__ void cast_bf16_kernel(const float* __restrict__ in,
                                 unsigned short* __restrict__ out, int n8) {
  int i = blockIdx.x * blockDim.x + threadIdx.x;
  if (i >= n8) return;
  const float4* p = (const float4*)(in + (size_t)i * 8);
  float4 a = p[0], b = p[1];
  union { unsigned short h[8]; bf16x8 v; } u;
  u.h[0] = f2b(a.x); u.h[1] = f2b(a.y); u.h[2] = f2b(a.z); u.h[3] = f2b(a.w);
  u.h[4] = f2b(b.x); u.h[5] = f2b(b.y); u.h[6] = f2b(b.z); u.h[7] = f2b(b.w);
  *(bf16x8*)(out + (size_t)i * 8) = u.v;
}

// ---------------- RoPE (in-place on bf16 Q or K) ----------------
__global__ void rope_kernel(unsigned short* __restrict__ X,
                            const int* __restrict__ pos, int total) {
  int idx = blockIdx.x * blockDim.x + threadIdx.x;
  if (idx >= total) return;
  int row = idx / 96, ch = idx - row * 96;   // 96 = DM/8 chunks per token
  int s = row & (SLEN - 1);
  int col = ch * 8;
  int p0 = (col & 63) >> 1;                  // pair index base within head
  float ps = (float)pos[s];
  unsigned short* ptr = X + (size_t)row * DM + col;
  bf16x8 v = *(bf16x8*)ptr;
  float f[8];
#pragma unroll
  for (int i = 0; i < 8; ++i) f[i] = b2f(((unsigned short*)&v)[i]);
  union { unsigned short h[8]; bf16x8 v; } o;
#pragma unroll
  for (int i = 0; i < 4; ++i) {
    float p = (float)(p0 + i);
    float freq = exp2f(p * -0.4152410118609203f);  // 10000^(-p/32)
    float ang = ps * freq;
    float sn, cs;
    __sincosf(ang, &sn, &cs);
    float x1 = f[2 * i], x2 = f[2 * i + 1];
    o.h[2 * i]     = f2b(x1 * cs - x2 * sn);
    o.h[2 * i + 1] = f2b(x1 * sn + x2 * cs);
  }
  *(bf16x8*)ptr = o.v;
}

// ---------------- GEMM: C[M][N] = sum_k A[m][k] * B[n][k] ----------------
__device__ __forceinline__ void stv(float* p, float v) { *p = v; }
__device__ __forceinline__ void stv(unsigned short* p, float v) { *p = f2b(v); }

template <typename CT>
__global__ __launch_bounds__(256, 2) void gemm_bt_kernel(
    const unsigned short* __restrict__ A,
    const unsigned short* __restrict__ B0, const unsigned short* __restrict__ B1,
    const unsigned short* __restrict__ B2,
    CT* __restrict__ C0, CT* __restrict__ C1, CT* __restrict__ C2,
    int N, int K) {
  const unsigned short* Bp = (blockIdx.z == 0) ? B0 : (blockIdx.z == 1) ? B1 : B2;
  CT* Cp = (blockIdx.z == 0) ? C0 : (blockIdx.z == 1) ? C1 : C2;
  const int tid = threadIdx.x, wid = tid >> 6, lane = tid & 63;
  const int lrow = lane & 15, lk8 = (lane >> 4) << 3;
  const int m0 = blockIdx.y * 128, n0 = blockIdx.x * 128;
  const int wm = (wid >> 1) * 64, wn = (wid & 1) * 64;
  const int sr = lane >> 3, sc = (lane & 7) * 8;
  __shared__ unsigned short At[128 * 64];
  __shared__ unsigned short Bt[128 * 64];
  f32x4 acc[4][4] = {};
  for (int k0 = 0; k0 < K; k0 += 64) {
    __syncthreads();
#pragma unroll
    for (int i = 0; i < 4; ++i) {
      int r = (wid * 4 + i) * 8 + sr;
      int k = sc ^ ((r & 7) << 3);
      gld16(A  + (size_t)(m0 + r) * K + k0 + k, &At[(wid * 4 + i) * 512]);
      gld16(Bp + (size_t)(n0 + r) * K + k0 + k, &Bt[(wid * 4 + i) * 512]);
    }
    __syncthreads();
    bf16x8 af[2][4], bfr[2][4];
#pragma unroll
    for (int ks = 0; ks < 2; ++ks)
#pragma unroll
      for (int mi = 0; mi < 4; ++mi) {
        int ra = wm + mi * 16 + lrow;
        af[ks][mi]  = *(const bf16x8*)&At[ra * 64 + ((ks * 32 + lk8) ^ ((ra & 7) << 3))];
        int rb = wn + mi * 16 + lrow;
        bfr[ks][mi] = *(const bf16x8*)&Bt[rb * 64 + ((ks * 32 + lk8) ^ ((rb & 7) << 3))];
      }
#pragma unroll
    for (int ks = 0; ks < 2; ++ks)
#pragma unroll
      for (int mi = 0; mi < 4; ++mi)
#pragma unroll
        for (int ni = 0; ni < 4; ++ni)
          acc[mi][ni] = __builtin_amdgcn_mfma_f32_16x16x32_bf16(
              af[ks][mi], bfr[ks][ni], acc[mi][ni], 0, 0, 0);
  }
#pragma unroll
  for (int mi = 0; mi < 4; ++mi)
#pragma unroll
    for (int ni = 0; ni < 4; ++ni)
#pragma unroll
      for (int r = 0; r < 4; ++r) {
        int row = m0 + wm + mi * 16 + (lane >> 4) * 4 + r;
        int col = n0 + wn + ni * 16 + lrow;
        stv(Cp + (size_t)row * N + col, acc[mi][ni][r]);
      }
}

// ---------------- V transpose (per head) with PV virtual-k permutation -------
// VT[bh][d][S]: storage col S = tt*64 + s holds V[token = tt*64 + pi(s)][d]
// where pi(s) = (s&32) + 16*((s&7)>>2) + 4*((s>>3)&3) + (s&3). This makes each
// PV A-fragment a single contiguous 16B load in the attention kernel.
__global__ void transpose_v_kernel(const unsigned short* __restrict__ V,
                                   unsigned short* __restrict__ VT) {
  const int tt = blockIdx.x, bh = blockIdx.y;
  const int b = bh / NH, h = bh - b * NH;
  const unsigned short* src = V + ((size_t)b * SLEN + tt * 64) * DM + h * DKH;
  unsigned short* dst = VT + (size_t)bh * DKH * SLEN + tt * 64;
  __shared__ unsigned short lds[64][72];
  const int tid = threadIdx.x;
  const int r = tid >> 2, cq = tid & 3;
#pragma unroll
  for (int pass = 0; pass < 2; ++pass) {
    int c = cq * 8 + pass * 32;
    *(bf16x8*)&lds[r][c] = *(const bf16x8*)&src[(size_t)r * DM + c];
  }
  __syncthreads();
  const int d = tid >> 2;
#pragma unroll
  for (int pass = 0; pass < 2; ++pass) {
    int s0 = cq * 8 + pass * 32;
    union { unsigned short h[8]; bf16x8 v; } o;
#pragma unroll
    for (int j = 0; j < 8; ++j) {
      int pi = pass * 32 + 16 * (j >> 2) + 4 * cq + (j & 3);
      o.h[j] = lds[pi][d];
    }
    *(bf16x8*)&dst[(size_t)d * SLEN + s0] = o.v;
  }
}

// ---------------- causal flash attention: barrier-free, LDS-free -------------
// One independent wave per block, 32 q-rows each. Swapped QK^T => lane-local
// softmax. Defer-max (THR=8): fast path has NO cross-lane ops and NO rescale;
// l accumulated per-lane, reduced across the 4 lane-groups once in epilogue.
// P packed with v_cvt_pk_bf16_f32. K dbuf 1 tile ahead; V from pre-permuted VT.
__global__ __launch_bounds__(64, 4) void attn_kernel(
    const unsigned short* __restrict__ Q, const unsigned short* __restrict__ Kg,
    const unsigned short* __restrict__ VT, unsigned short* __restrict__ O) {
  const int i = blockIdx.x;
  const int qw = 63 - (i / 48);
  const int bh = i % 48;
  const int b = bh / NH, h = bh - b * NH;
  const size_t base = ((size_t)b * SLEN) * DM + h * DKH;
  const size_t vbase = (size_t)bh * DKH * SLEN;
  const int lane = threadIdx.x;
  const int lrow = lane & 15, g = lane >> 4;

  // Q fragments (B operand of swapped QK^T), scaled by 0.125*log2(e)
  bf16x8 qf[2][2];
#pragma unroll
  for (int mi = 0; mi < 2; ++mi)
#pragma unroll
    for (int ks = 0; ks < 2; ++ks) {
      const int qrow = qw * 32 + mi * 16 + lrow;
      union { unsigned short h[8]; bf16x8 v; } u;
      u.v = *(const bf16x8*)&Q[base + (size_t)qrow * DM + ks * 32 + g * 8];
#pragma unroll
      for (int j = 0; j < 8; ++j)
        u.h[j] = f2b(b2f(u.h[j]) * 0.18033688011112042f);
      qf[mi][ks] = u.v;
    }

  f32x4 oacc[2][4] = {};
  float m_run[2] = {-1e30f, -1e30f};
  float l_part[2] = {0.f, 0.f};          // per-lane partial denominators
  const int qg0 = qw * 32 + lrow;
  const int nkt = (qw >> 1) + 1;

  bf16x8 kA[8], kB[8], vA[8];

  auto loadK = [&](int t, bf16x8* kf) {
#pragma unroll
    for (int ks = 0; ks < 2; ++ks)
#pragma unroll
      for (int ni = 0; ni < 4; ++ni)
        kf[ks * 4 + ni] = *(const bf16x8*)
            &Kg[base + (size_t)(t * 64 + ni * 16 + lrow) * DM + ks * 32 + g * 8];
  };
  auto loadV = [&](int t, bf16x8* vf) {
#pragma unroll
    for (int ks = 0; ks < 2; ++ks)
#pragma unroll
      for (int ni = 0; ni < 4; ++ni)
        vf[ks * 4 + ni] = *(const bf16x8*)
            &VT[vbase + (size_t)(ni * 16 + lrow) * SLEN + t * 64 + ks * 32 + g * 8];
  };

  auto compute = [&](int t, bf16x8* kf, bf16x8* vf) {
    // S^T = K Q^T : sa[mi][ni][r] = S[q=mi*16+lrow][k=t*64+ni*16+g*4+r] (log2)
    f32x4 sa[2][4] = {};
    __builtin_amdgcn_s_setprio(1);
#pragma unroll
    for (int ks = 0; ks < 2; ++ks)
#pragma unroll
      for (int ni = 0; ni < 4; ++ni)
#pragma unroll
        for (int mi = 0; mi < 2; ++mi)
          sa[mi][ni] = __builtin_amdgcn_mfma_f32_16x16x32_bf16(
              kf[ks * 4 + ni], qf[mi][ks], sa[mi][ni], 0, 0, 0);
    __builtin_amdgcn_s_setprio(0);

    const bool need_mask = (t * 64 + 64 > qw * 32);   // final tile only
    if (need_mask) {
      const int kb = t * 64 + g * 4;
#pragma unroll
      for (int mi = 0; mi < 2; ++mi) {
        const int qg = qg0 + mi * 16;
#pragma unroll
        for (int ni = 0; ni < 4; ++ni)
#pragma unroll
          for (int r = 0; r < 4; ++r)
            if (kb + ni * 16 + r > qg) sa[mi][ni][r] = -1e30f;
      }
    }

    // lane-local 16-element max (no cross-lane in fast path)
    float mx[2];
#pragma unroll
    for (int mi = 0; mi < 2; ++mi) {
      f32x4 t01, t23;
#pragma unroll
      for (int r = 0; r < 4; ++r) {
        t01[r] = fmaxf(sa[mi][0][r], sa[mi][1][r]);
        t23[r] = fmaxf(sa[mi][2][r], sa[mi][3][r]);
      }
      float a = fmaxf(fmaxf(t01[0], t23[0]), fmaxf(t01[1], t23[1]));
      float c = fmaxf(fmaxf(t01[2], t23[2]), fmaxf(t01[3], t23[3]));
      mx[mi] = fmaxf(a, c);
    }

    // defer-max: slow path only if some lane's local max exceeds m_run+8
    const int viol = (mx[0] > m_run[0] + 8.f) || (mx[1] > m_run[1] + 8.f);
    if (__any(viol)) {
#pragma unroll
      for (int mi = 0; mi < 2; ++mi) {
        float mr = fmaxf(mx[mi], __shfl_xor(mx[mi], 16));
        mr = fmaxf(mr, __shfl_xor(mr, 32));
        float mn = fmaxf(m_run[mi], mr);
        float scl = exp2f(m_run[mi] - mn);
        m_run[mi] = mn;
        l_part[mi] *= scl;
#pragma unroll
        for (int ni = 0; ni < 4; ++ni) oacc[mi][ni] *= scl;
      }
    }

    // exp2 (P bounded by 2^8) + per-lane l accumulation
#pragma unroll
    for (int mi = 0; mi < 2; ++mi) {
      float s0 = 0.f;
#pragma unroll
      for (int ni = 0; ni < 4; ++ni)
#pragma unroll
        for (int r = 0; r < 4; ++r) {
          float e = exp2f(sa[mi][ni][r] - m_run[mi]);
          sa[mi][ni][r] = e;
          s0 += e;
        }
      l_part[mi] += s0;
    }

    // pack P lane-local via cvt_pk (virtual kv = ks*32+g*8+j matches VT perm)
    bf16x8 pf[2][2];
#pragma unroll
    for (int mi = 0; mi < 2; ++mi)
#pragma unroll
      for (int ks = 0; ks < 2; ++ks) {
        union { unsigned u[4]; bf16x8 v; } uu;
        uu.u[0] = cvtpk(sa[mi][2 * ks][0],     sa[mi][2 * ks][1]);
        uu.u[1] = cvtpk(sa[mi][2 * ks][2],     sa[mi][2 * ks][3]);
        uu.u[2] = cvtpk(sa[mi][2 * ks + 1][0], sa[mi][2 * ks + 1][1]);
        uu.u[3] = cvtpk(sa[mi][2 * ks + 1][2], sa[mi][2 * ks + 1][3]);
        pf[mi][ks] = uu.v;
      }

    // O^T += V^T P^T (A = VT frag, pre-permuted storage)
    __builtin_amdgcn_s_setprio(1);
#pragma unroll
    for (int ks = 0; ks < 2; ++ks)
#pragma unroll
      for (int ni = 0; ni < 4; ++ni)
#pragma unroll
        for (int mi = 0; mi < 2; ++mi)
          oacc[mi][ni] = __builtin_amdgcn_mfma_f32_16x16x32_bf16(
              vf[ks * 4 + ni], pf[mi][ks], oacc[mi][ni], 0, 0, 0);
    __builtin_amdgcn_s_setprio(0);
  };

  loadK(0, kA);
  for (int t = 0; t < nkt; t += 2) {
    loadV(t, vA);
    if (t + 1 < nkt) loadK(t + 1, kB);
    compute(t, kA, vA);
    if (t + 1 < nkt) {
      loadV(t + 1, vA);               // after PV of tile t (reg WAR dep)
      if (t + 2 < nkt) loadK(t + 2, kA);
      compute(t + 1, kB, vA);
    }
  }

  // epilogue: reduce l across the 4 lane-groups once; store O
#pragma unroll
  for (int mi = 0; mi < 2; ++mi) {
    float l = l_part[mi];
    l += __shfl_xor(l, 16);
    l += __shfl_xor(l, 32);
    const float inv = 1.f / l;
    const int qrow = qw * 32 + mi * 16 + lrow;
#pragma unroll
    for (int ni = 0; ni < 4; ++ni) {
      union { unsigned u[2]; ushort4 s; } o;
      o.u[0] = cvtpk(oacc[mi][ni][0] * inv, oacc[mi][ni][1] * inv);
      o.u[1] = cvtpk(oacc[mi][ni][2] * inv, oacc[mi][ni][3] * inv);
      *(ushort4*)&O[base + (size_t)qrow * DM + ni * 16 + g * 4] = o.s;
    }
  }
}

// ---------------- launch ----------------
extern "C" void kernel_launch(void* const* d_in, const int* in_sizes, int n_in,
                              void* d_out, int out_size, void* d_ws, size_t ws_size,
                              hipStream_t stream) {
  const float* x  = (const float*)d_in[0];
  const float* Wq = (const float*)d_in[1];
  const float* Wk = (const float*)d_in[2];
  const float* Wv = (const float*)d_in[3];
  const float* Wo = (const float*)d_in[4];
  const int* pos  = (const int*)d_in[5];
  float* out = (float*)d_out;

  char* ws = (char*)d_ws;
  size_t off = 0;
  auto carve = [&](size_t bytes) -> void* {
    void* p = ws + off;
    off += (bytes + 255) & ~(size_t)255;
    return p;
  };
  unsigned short* xb  = (unsigned short*)carve((size_t)NTOK * DM * 2);
  unsigned short* wqb = (unsigned short*)carve((size_t)DM * DM * 2);
  unsigned short* wkb = (unsigned short*)carve((size_t)DM * DM * 2);
  unsigned short* wvb = (unsigned short*)carve((size_t)DM * DM * 2);
  unsigned short* wob = (unsigned short*)carve((size_t)DM * DM * 2);
  unsigned short* Qb  = (unsigned short*)carve((size_t)NTOK * DM * 2);
  unsigned short* Kb  = (unsigned short*)carve((size_t)NTOK * DM * 2);
  unsigned short* Vb  = (unsigned short*)carve((size_t)NTOK * DM * 2);
  unsigned short* Ab  = (unsigned short*)carve((size_t)NTOK * DM * 2);
  unsigned short* VTb = (unsigned short*)carve((size_t)4 * NH * DKH * SLEN * 2);

  const int n8x = NTOK * DM / 8;   // 786432
  const int n8w = DM * DM / 8;     // 73728
  cast_bf16_kernel<<<dim3((n8x + 255) / 256), dim3(256), 0, stream>>>(x, xb, n8x);
  cast_bf16_kernel<<<dim3((n8w + 255) / 256), dim3(256), 0, stream>>>(Wq, wqb, n8w);
  cast_bf16_kernel<<<dim3((n8w + 255) / 256), dim3(256), 0, stream>>>(Wk, wkb, n8w);
  cast_bf16_kernel<<<dim3((n8w + 255) / 256), dim3(256), 0, stream>>>(Wv, wvb, n8w);
  cast_bf16_kernel<<<dim3((n8w + 255) / 256), dim3(256), 0, stream>>>(Wo, wob, n8w);

  gemm_bt_kernel<unsigned short><<<dim3(6, 64, 3), dim3(256), 0, stream>>>(
      xb, wqb, wkb, wvb, Qb, Kb, Vb, DM, DM);

  const int nrope = NTOK * (DM / 8);
  rope_kernel<<<dim3((nrope + 255) / 256), dim3(256), 0, stream>>>(Qb, pos, nrope);
  rope_kernel<<<dim3((nrope + 255) / 256), dim3(256), 0, stream>>>(Kb, pos, nrope);

  transpose_v_kernel<<<dim3(SLEN / 64, 4 * NH), dim3(256), 0, stream>>>(Vb, VTb);

  attn_kernel<<<dim3(64 * 48), dim3(64), 0, stream>>>(Qb, Kb, VTb, Ab);

  gemm_bt_kernel<float><<<dim3(6, 64, 1), dim3(256), 0, stream>>>(
      Ab, wob, wob, wob, out, out, out, DM, DM);
}

// Round 7
// 187.635 us; speedup vs baseline: 1.7180x; 1.7180x over previous
//
#include <hip/hip_runtime.h>
#include <cstdint>
#include <cstddef>

#define NTOK 8192      // B*S
#define SLEN 2048
#define DM   768
#define NH   12
#define DKH  64

typedef __attribute__((ext_vector_type(8))) short bf16x8;
typedef __attribute__((ext_vector_type(4))) float f32x4;

__device__ __forceinline__ float b2f(unsigned short u) {
  return __uint_as_float(((unsigned)u) << 16);
}
__device__ __forceinline__ unsigned short f2b(float f) {
  unsigned u = __float_as_uint(f);
  u += 0x7fffu + ((u >> 16) & 1u);   // RNE (no NaN inputs here)
  return (unsigned short)(u >> 16);
}
__device__ __forceinline__ unsigned cvtpk(float lo, float hi) {
  unsigned r;
  asm("v_cvt_pk_bf16_f32 %0, %1, %2" : "=v"(r) : "v"(lo), "v"(hi));
  return r;
}

__device__ __forceinline__ void gld16(const void* g, void* l) {
  __builtin_amdgcn_global_load_lds(
      (const __attribute__((address_space(1))) void*)g,
      (__attribute__((address_space(3))) void*)l, 16, 0, 0);
}

// ---------------- fp32 -> bf16 cast ----------------
__global__ void cast_bf16_kernel(const float* __restrict__ in,
                                 unsigned short* __restrict__ out, int n8) {
  int i = blockIdx.x * blockDim.x + threadIdx.x;
  if (i >= n8) return;
  const float4* p = (const float4*)(in + (size_t)i * 8);
  float4 a = p[0], b = p[1];
  union { unsigned short h[8]; bf16x8 v; } u;
  u.h[0] = f2b(a.x); u.h[1] = f2b(a.y); u.h[2] = f2b(a.z); u.h[3] = f2b(a.w);
  u.h[4] = f2b(b.x); u.h[5] = f2b(b.y); u.h[6] = f2b(b.z); u.h[7] = f2b(b.w);
  *(bf16x8*)(out + (size_t)i * 8) = u.v;
}

// ---------------- RoPE (in-place on bf16 Q or K) ----------------
__global__ void rope_kernel(unsigned short* __restrict__ X,
                            const int* __restrict__ pos, int total) {
  int idx = blockIdx.x * blockDim.x + threadIdx.x;
  if (idx >= total) return;
  int row = idx / 96, ch = idx - row * 96;   // 96 = DM/8 chunks per token
  int s = row & (SLEN - 1);
  int col = ch * 8;
  int p0 = (col & 63) >> 1;                  // pair index base within head
  float ps = (float)pos[s];
  unsigned short* ptr = X + (size_t)row * DM + col;
  bf16x8 v = *(bf16x8*)ptr;
  float f[8];
#pragma unroll
  for (int i = 0; i < 8; ++i) f[i] = b2f(((unsigned short*)&v)[i]);
  union { unsigned short h[8]; bf16x8 v; } o;
#pragma unroll
  for (int i = 0; i < 4; ++i) {
    float p = (float)(p0 + i);
    float freq = exp2f(p * -0.4152410118609203f);  // 10000^(-p/32)
    float ang = ps * freq;
    float sn, cs;
    __sincosf(ang, &sn, &cs);
    float x1 = f[2 * i], x2 = f[2 * i + 1];
    o.h[2 * i]     = f2b(x1 * cs - x2 * sn);
    o.h[2 * i + 1] = f2b(x1 * sn + x2 * cs);
  }
  *(bf16x8*)ptr = o.v;
}

// ---------------- GEMM: C[M][N] = sum_k A[m][k] * B[n][k] ----------------
__device__ __forceinline__ void stv(float* p, float v) { *p = v; }
__device__ __forceinline__ void stv(unsigned short* p, float v) { *p = f2b(v); }

template <typename CT>
__global__ __launch_bounds__(256, 2) void gemm_bt_kernel(
    const unsigned short* __restrict__ A,
    const unsigned short* __restrict__ B0, const unsigned short* __restrict__ B1,
    const unsigned short* __restrict__ B2,
    CT* __restrict__ C0, CT* __restrict__ C1, CT* __restrict__ C2,
    int N, int K) {
  const unsigned short* Bp = (blockIdx.z == 0) ? B0 : (blockIdx.z == 1) ? B1 : B2;
  CT* Cp = (blockIdx.z == 0) ? C0 : (blockIdx.z == 1) ? C1 : C2;
  const int tid = threadIdx.x, wid = tid >> 6, lane = tid & 63;
  const int lrow = lane & 15, lk8 = (lane >> 4) << 3;
  const int m0 = blockIdx.y * 128, n0 = blockIdx.x * 128;
  const int wm = (wid >> 1) * 64, wn = (wid & 1) * 64;
  const int sr = lane >> 3, sc = (lane & 7) * 8;
  __shared__ unsigned short At[128 * 64];
  __shared__ unsigned short Bt[128 * 64];
  f32x4 acc[4][4] = {};
  for (int k0 = 0; k0 < K; k0 += 64) {
    __syncthreads();
#pragma unroll
    for (int i = 0; i < 4; ++i) {
      int r = (wid * 4 + i) * 8 + sr;
      int k = sc ^ ((r & 7) << 3);
      gld16(A  + (size_t)(m0 + r) * K + k0 + k, &At[(wid * 4 + i) * 512]);
      gld16(Bp + (size_t)(n0 + r) * K + k0 + k, &Bt[(wid * 4 + i) * 512]);
    }
    __syncthreads();
    bf16x8 af[2][4], bfr[2][4];
#pragma unroll
    for (int ks = 0; ks < 2; ++ks)
#pragma unroll
      for (int mi = 0; mi < 4; ++mi) {
        int ra = wm + mi * 16 + lrow;
        af[ks][mi]  = *(const bf16x8*)&At[ra * 64 + ((ks * 32 + lk8) ^ ((ra & 7) << 3))];
        int rb = wn + mi * 16 + lrow;
        bfr[ks][mi] = *(const bf16x8*)&Bt[rb * 64 + ((ks * 32 + lk8) ^ ((rb & 7) << 3))];
      }
#pragma unroll
    for (int ks = 0; ks < 2; ++ks)
#pragma unroll
      for (int mi = 0; mi < 4; ++mi)
#pragma unroll
        for (int ni = 0; ni < 4; ++ni)
          acc[mi][ni] = __builtin_amdgcn_mfma_f32_16x16x32_bf16(
              af[ks][mi], bfr[ks][ni], acc[mi][ni], 0, 0, 0);
  }
#pragma unroll
  for (int mi = 0; mi < 4; ++mi)
#pragma unroll
    for (int ni = 0; ni < 4; ++ni)
#pragma unroll
      for (int r = 0; r < 4; ++r) {
        int row = m0 + wm + mi * 16 + (lane >> 4) * 4 + r;
        int col = n0 + wn + ni * 16 + lrow;
        stv(Cp + (size_t)row * N + col, acc[mi][ni][r]);
      }
}

// ---------------- V transpose (per head) with PV virtual-k permutation -------
// VT[bh][d][S]: storage col S = tt*64 + s holds V[token = tt*64 + pi(s)][d]
// where pi(s) = (s&32) + 16*((s&7)>>2) + 4*((s>>3)&3) + (s&3). This makes each
// PV A-fragment a single contiguous 16B load in the attention kernel.
__global__ void transpose_v_kernel(const unsigned short* __restrict__ V,
                                   unsigned short* __restrict__ VT) {
  const int tt = blockIdx.x, bh = blockIdx.y;
  const int b = bh / NH, h = bh - b * NH;
  const unsigned short* src = V + ((size_t)b * SLEN + tt * 64) * DM + h * DKH;
  unsigned short* dst = VT + (size_t)bh * DKH * SLEN + tt * 64;
  __shared__ unsigned short lds[64][72];
  const int tid = threadIdx.x;
  const int r = tid >> 2, cq = tid & 3;
#pragma unroll
  for (int pass = 0; pass < 2; ++pass) {
    int c = cq * 8 + pass * 32;
    *(bf16x8*)&lds[r][c] = *(const bf16x8*)&src[(size_t)r * DM + c];
  }
  __syncthreads();
  const int d = tid >> 2;
#pragma unroll
  for (int pass = 0; pass < 2; ++pass) {
    int s0 = cq * 8 + pass * 32;
    union { unsigned short h[8]; bf16x8 v; } o;
#pragma unroll
    for (int j = 0; j < 8; ++j) {
      int pi = pass * 32 + 16 * (j >> 2) + 4 * cq + (j & 3);
      o.h[j] = lds[pi][d];
    }
    *(bf16x8*)&dst[(size_t)d * SLEN + s0] = o.v;
  }
}

// ---------------- causal flash attention: barrier-free, LDS-free -------------
// One independent wave per block, 32 q-rows each. Swapped QK^T => lane-local
// softmax. Defer-max (THR=8): fast path has NO cross-lane ops and NO rescale;
// l accumulated per-lane, reduced across the 4 lane-groups once in epilogue.
// P packed with v_cvt_pk_bf16_f32. K dbuf 1 tile ahead; V from pre-permuted VT.
// NOTE: __launch_bounds__ MUST stay (64,2): (64,4) caps VGPR below the 96-reg
// K/V staging and spills everything to scratch (431MB writes, 2x slower, r6).
__global__ __launch_bounds__(64, 2) void attn_kernel(
    const unsigned short* __restrict__ Q, const unsigned short* __restrict__ Kg,
    const unsigned short* __restrict__ VT, unsigned short* __restrict__ O) {
  const int i = blockIdx.x;
  const int qw = 63 - (i / 48);
  const int bh = i % 48;
  const int b = bh / NH, h = bh - b * NH;
  const size_t base = ((size_t)b * SLEN) * DM + h * DKH;
  const size_t vbase = (size_t)bh * DKH * SLEN;
  const int lane = threadIdx.x;
  const int lrow = lane & 15, g = lane >> 4;

  // Q fragments (B operand of swapped QK^T), scaled by 0.125*log2(e)
  bf16x8 qf[2][2];
#pragma unroll
  for (int mi = 0; mi < 2; ++mi)
#pragma unroll
    for (int ks = 0; ks < 2; ++ks) {
      const int qrow = qw * 32 + mi * 16 + lrow;
      union { unsigned short h[8]; bf16x8 v; } u;
      u.v = *(const bf16x8*)&Q[base + (size_t)qrow * DM + ks * 32 + g * 8];
#pragma unroll
      for (int j = 0; j < 8; ++j)
        u.h[j] = f2b(b2f(u.h[j]) * 0.18033688011112042f);
      qf[mi][ks] = u.v;
    }

  f32x4 oacc[2][4] = {};
  float m_run[2] = {-1e30f, -1e30f};
  float l_part[2] = {0.f, 0.f};          // per-lane partial denominators
  const int qg0 = qw * 32 + lrow;
  const int nkt = (qw >> 1) + 1;

  bf16x8 kA[8], kB[8], vA[8];

  auto loadK = [&](int t, bf16x8* kf) {
#pragma unroll
    for (int ks = 0; ks < 2; ++ks)
#pragma unroll
      for (int ni = 0; ni < 4; ++ni)
        kf[ks * 4 + ni] = *(const bf16x8*)
            &Kg[base + (size_t)(t * 64 + ni * 16 + lrow) * DM + ks * 32 + g * 8];
  };
  auto loadV = [&](int t, bf16x8* vf) {
#pragma unroll
    for (int ks = 0; ks < 2; ++ks)
#pragma unroll
      for (int ni = 0; ni < 4; ++ni)
        vf[ks * 4 + ni] = *(const bf16x8*)
            &VT[vbase + (size_t)(ni * 16 + lrow) * SLEN + t * 64 + ks * 32 + g * 8];
  };

  auto compute = [&](int t, bf16x8* kf, bf16x8* vf) {
    // S^T = K Q^T : sa[mi][ni][r] = S[q=mi*16+lrow][k=t*64+ni*16+g*4+r] (log2)
    f32x4 sa[2][4] = {};
    __builtin_amdgcn_s_setprio(1);
#pragma unroll
    for (int ks = 0; ks < 2; ++ks)
#pragma unroll
      for (int ni = 0; ni < 4; ++ni)
#pragma unroll
        for (int mi = 0; mi < 2; ++mi)
          sa[mi][ni] = __builtin_amdgcn_mfma_f32_16x16x32_bf16(
              kf[ks * 4 + ni], qf[mi][ks], sa[mi][ni], 0, 0, 0);
    __builtin_amdgcn_s_setprio(0);

    const bool need_mask = (t * 64 + 64 > qw * 32);   // final tile only
    if (need_mask) {
      const int kb = t * 64 + g * 4;
#pragma unroll
      for (int mi = 0; mi < 2; ++mi) {
        const int qg = qg0 + mi * 16;
#pragma unroll
        for (int ni = 0; ni < 4; ++ni)
#pragma unroll
          for (int r = 0; r < 4; ++r)
            if (kb + ni * 16 + r > qg) sa[mi][ni][r] = -1e30f;
      }
    }

    // lane-local 16-element max (no cross-lane in fast path)
    float mx[2];
#pragma unroll
    for (int mi = 0; mi < 2; ++mi) {
      f32x4 t01, t23;
#pragma unroll
      for (int r = 0; r < 4; ++r) {
        t01[r] = fmaxf(sa[mi][0][r], sa[mi][1][r]);
        t23[r] = fmaxf(sa[mi][2][r], sa[mi][3][r]);
      }
      float a = fmaxf(fmaxf(t01[0], t23[0]), fmaxf(t01[1], t23[1]));
      float c = fmaxf(fmaxf(t01[2], t23[2]), fmaxf(t01[3], t23[3]));
      mx[mi] = fmaxf(a, c);
    }

    // defer-max: slow path only if some lane's local max exceeds m_run+8
    const int viol = (mx[0] > m_run[0] + 8.f) || (mx[1] > m_run[1] + 8.f);
    if (__any(viol)) {
#pragma unroll
      for (int mi = 0; mi < 2; ++mi) {
        float mr = fmaxf(mx[mi], __shfl_xor(mx[mi], 16));
        mr = fmaxf(mr, __shfl_xor(mr, 32));
        float mn = fmaxf(m_run[mi], mr);
        float scl = exp2f(m_run[mi] - mn);
        m_run[mi] = mn;
        l_part[mi] *= scl;
#pragma unroll
        for (int ni = 0; ni < 4; ++ni) oacc[mi][ni] *= scl;
      }
    }

    // exp2 (P bounded by 2^8) + per-lane l accumulation
#pragma unroll
    for (int mi = 0; mi < 2; ++mi) {
      float s0 = 0.f;
#pragma unroll
      for (int ni = 0; ni < 4; ++ni)
#pragma unroll
        for (int r = 0; r < 4; ++r) {
          float e = exp2f(sa[mi][ni][r] - m_run[mi]);
          sa[mi][ni][r] = e;
          s0 += e;
        }
      l_part[mi] += s0;
    }

    // pack P lane-local via cvt_pk (virtual kv = ks*32+g*8+j matches VT perm)
    bf16x8 pf[2][2];
#pragma unroll
    for (int mi = 0; mi < 2; ++mi)
#pragma unroll
      for (int ks = 0; ks < 2; ++ks) {
        union { unsigned u[4]; bf16x8 v; } uu;
        uu.u[0] = cvtpk(sa[mi][2 * ks][0],     sa[mi][2 * ks][1]);
        uu.u[1] = cvtpk(sa[mi][2 * ks][2],     sa[mi][2 * ks][3]);
        uu.u[2] = cvtpk(sa[mi][2 * ks + 1][0], sa[mi][2 * ks + 1][1]);
        uu.u[3] = cvtpk(sa[mi][2 * ks + 1][2], sa[mi][2 * ks + 1][3]);
        pf[mi][ks] = uu.v;
      }

    // O^T += V^T P^T (A = VT frag, pre-permuted storage)
    __builtin_amdgcn_s_setprio(1);
#pragma unroll
    for (int ks = 0; ks < 2; ++ks)
#pragma unroll
      for (int ni = 0; ni < 4; ++ni)
#pragma unroll
        for (int mi = 0; mi < 2; ++mi)
          oacc[mi][ni] = __builtin_amdgcn_mfma_f32_16x16x32_bf16(
              vf[ks * 4 + ni], pf[mi][ks], oacc[mi][ni], 0, 0, 0);
    __builtin_amdgcn_s_setprio(0);
  };

  loadK(0, kA);
  for (int t = 0; t < nkt; t += 2) {
    loadV(t, vA);
    if (t + 1 < nkt) loadK(t + 1, kB);
    compute(t, kA, vA);
    if (t + 1 < nkt) {
      loadV(t + 1, vA);               // after PV of tile t (reg WAR dep)
      if (t + 2 < nkt) loadK(t + 2, kA);
      compute(t + 1, kB, vA);
    }
  }

  // epilogue: reduce l across the 4 lane-groups once; store O
#pragma unroll
  for (int mi = 0; mi < 2; ++mi) {
    float l = l_part[mi];
    l += __shfl_xor(l, 16);
    l += __shfl_xor(l, 32);
    const float inv = 1.f / l;
    const int qrow = qw * 32 + mi * 16 + lrow;
#pragma unroll
    for (int ni = 0; ni < 4; ++ni) {
      union { unsigned u[2]; ushort4 s; } o;
      o.u[0] = cvtpk(oacc[mi][ni][0] * inv, oacc[mi][ni][1] * inv);
      o.u[1] = cvtpk(oacc[mi][ni][2] * inv, oacc[mi][ni][3] * inv);
      *(ushort4*)&O[base + (size_t)qrow * DM + ni * 16 + g * 4] = o.s;
    }
  }
}

// ---------------- launch ----------------
extern "C" void kernel_launch(void* const* d_in, const int* in_sizes, int n_in,
                              void* d_out, int out_size, void* d_ws, size_t ws_size,
                              hipStream_t stream) {
  const float* x  = (const float*)d_in[0];
  const float* Wq = (const float*)d_in[1];
  const float* Wk = (const float*)d_in[2];
  const float* Wv = (const float*)d_in[3];
  const float* Wo = (const float*)d_in[4];
  const int* pos  = (const int*)d_in[5];
  float* out = (float*)d_out;

  char* ws = (char*)d_ws;
  size_t off = 0;
  auto carve = [&](size_t bytes) -> void* {
    void* p = ws + off;
    off += (bytes + 255) & ~(size_t)255;
    return p;
  };
  unsigned short* xb  = (unsigned short*)carve((size_t)NTOK * DM * 2);
  unsigned short* wqb = (unsigned short*)carve((size_t)DM * DM * 2);
  unsigned short* wkb = (unsigned short*)carve((size_t)DM * DM * 2);
  unsigned short* wvb = (unsigned short*)carve((size_t)DM * DM * 2);
  unsigned short* wob = (unsigned short*)carve((size_t)DM * DM * 2);
  unsigned short* Qb  = (unsigned short*)carve((size_t)NTOK * DM * 2);
  unsigned short* Kb  = (unsigned short*)carve((size_t)NTOK * DM * 2);
  unsigned short* Vb  = (unsigned short*)carve((size_t)NTOK * DM * 2);
  unsigned short* Ab  = (unsigned short*)carve((size_t)NTOK * DM * 2);
  unsigned short* VTb = (unsigned short*)carve((size_t)4 * NH * DKH * SLEN * 2);

  const int n8x = NTOK * DM / 8;   // 786432
  const int n8w = DM * DM / 8;     // 73728
  cast_bf16_kernel<<<dim3((n8x + 255) / 256), dim3(256), 0, stream>>>(x, xb, n8x);
  cast_bf16_kernel<<<dim3((n8w + 255) / 256), dim3(256), 0, stream>>>(Wq, wqb, n8w);
  cast_bf16_kernel<<<dim3((n8w + 255) / 256), dim3(256), 0, stream>>>(Wk, wkb, n8w);
  cast_bf16_kernel<<<dim3((n8w + 255) / 256), dim3(256), 0, stream>>>(Wv, wvb, n8w);
  cast_bf16_kernel<<<dim3((n8w + 255) / 256), dim3(256), 0, stream>>>(Wo, wob, n8w);

  gemm_bt_kernel<unsigned short><<<dim3(6, 64, 3), dim3(256), 0, stream>>>(
      xb, wqb, wkb, wvb, Qb, Kb, Vb, DM, DM);

  const int nrope = NTOK * (DM / 8);
  rope_kernel<<<dim3((nrope + 255) / 256), dim3(256), 0, stream>>>(Qb, pos, nrope);
  rope_kernel<<<dim3((nrope + 255) / 256), dim3(256), 0, stream>>>(Kb, pos, nrope);

  transpose_v_kernel<<<dim3(SLEN / 64, 4 * NH), dim3(256), 0, stream>>>(Vb, VTb);

  attn_kernel<<<dim3(64 * 48), dim3(64), 0, stream>>>(Qb, Kb, VTb, Ab);

  gemm_bt_kernel<float><<<dim3(6, 64, 1), dim3(256), 0, stream>>>(
      Ab, wob, wob, wob, out, out, out, DM, DM);
}

// Round 8
// 141.399 us; speedup vs baseline: 2.2798x; 1.3270x over previous
//
#include <hip/hip_runtime.h>
#include <cstdint>
#include <cstddef>

#define NTOK 8192      // B*S
#define SLEN 2048
#define DM   768
#define NH   12
#define DKH  64

typedef __attribute__((ext_vector_type(8))) short bf16x8;
typedef __attribute__((ext_vector_type(4))) float f32x4;

__device__ __forceinline__ float b2f(unsigned short u) {
  return __uint_as_float(((unsigned)u) << 16);
}
__device__ __forceinline__ unsigned short f2b(float f) {
  unsigned u = __float_as_uint(f);
  u += 0x7fffu + ((u >> 16) & 1u);   // RNE (no NaN inputs here)
  return (unsigned short)(u >> 16);
}
__device__ __forceinline__ unsigned cvtpk(float lo, float hi) {
  unsigned r;
  asm("v_cvt_pk_bf16_f32 %0, %1, %2" : "=v"(r) : "v"(lo), "v"(hi));
  return r;
}

__device__ __forceinline__ void gld16(const void* g, void* l) {
  __builtin_amdgcn_global_load_lds(
      (const __attribute__((address_space(1))) void*)g,
      (__attribute__((address_space(3))) void*)l, 16, 0, 0);
}

// one barrier per tile; vmcnt(0) is cheap here since per-tile compute
// (~800+ cyc) exceeds L2-hit latency of the staged loads.
#define TILE_BAR() do {                                   \
    asm volatile("s_waitcnt vmcnt(0)" ::: "memory");      \
    __builtin_amdgcn_s_barrier();                         \
    __builtin_amdgcn_sched_barrier(0);                    \
  } while (0)

// ---------------- fp32 -> bf16 cast ----------------
__global__ void cast_bf16_kernel(const float* __restrict__ in,
                                 unsigned short* __restrict__ out, int n8) {
  int i = blockIdx.x * blockDim.x + threadIdx.x;
  if (i >= n8) return;
  const float4* p = (const float4*)(in + (size_t)i * 8);
  float4 a = p[0], b = p[1];
  union { unsigned short h[8]; bf16x8 v; } u;
  u.h[0] = f2b(a.x); u.h[1] = f2b(a.y); u.h[2] = f2b(a.z); u.h[3] = f2b(a.w);
  u.h[4] = f2b(b.x); u.h[5] = f2b(b.y); u.h[6] = f2b(b.z); u.h[7] = f2b(b.w);
  *(bf16x8*)(out + (size_t)i * 8) = u.v;
}

// ---------------- GEMM: C[M][N] = sum_k A[m][k] * B[n][k] ----------------
// Optional fused RoPE on the f32 accumulator (z<2 when do_rope): pairs are
// adjacent cols -> one __shfl_xor(v,1); angle = pos[row%S] * 10000^(-p/32).
__device__ __forceinline__ void stv(float* p, float v) { *p = v; }
__device__ __forceinline__ void stv(unsigned short* p, float v) { *p = f2b(v); }

template <typename CT>
__global__ __launch_bounds__(256, 2) void gemm_bt_kernel(
    const unsigned short* __restrict__ A,
    const unsigned short* __restrict__ B0, const unsigned short* __restrict__ B1,
    const unsigned short* __restrict__ B2,
    CT* __restrict__ C0, CT* __restrict__ C1, CT* __restrict__ C2,
    int N, int K, const int* __restrict__ pos, int do_rope) {
  const unsigned short* Bp = (blockIdx.z == 0) ? B0 : (blockIdx.z == 1) ? B1 : B2;
  CT* Cp = (blockIdx.z == 0) ? C0 : (blockIdx.z == 1) ? C1 : C2;
  const int tid = threadIdx.x, wid = tid >> 6, lane = tid & 63;
  const int lrow = lane & 15, lk8 = (lane >> 4) << 3;
  const int m0 = blockIdx.y * 128, n0 = blockIdx.x * 128;
  const int wm = (wid >> 1) * 64, wn = (wid & 1) * 64;
  const int sr = lane >> 3, sc = (lane & 7) * 8;
  __shared__ unsigned short At[128 * 64];
  __shared__ unsigned short Bt[128 * 64];
  f32x4 acc[4][4] = {};
  for (int k0 = 0; k0 < K; k0 += 64) {
    __syncthreads();
#pragma unroll
    for (int i = 0; i < 4; ++i) {
      int r = (wid * 4 + i) * 8 + sr;
      int k = sc ^ ((r & 7) << 3);
      gld16(A  + (size_t)(m0 + r) * K + k0 + k, &At[(wid * 4 + i) * 512]);
      gld16(Bp + (size_t)(n0 + r) * K + k0 + k, &Bt[(wid * 4 + i) * 512]);
    }
    __syncthreads();
    bf16x8 af[2][4], bfr[2][4];
#pragma unroll
    for (int ks = 0; ks < 2; ++ks)
#pragma unroll
      for (int mi = 0; mi < 4; ++mi) {
        int ra = wm + mi * 16 + lrow;
        af[ks][mi]  = *(const bf16x8*)&At[ra * 64 + ((ks * 32 + lk8) ^ ((ra & 7) << 3))];
        int rb = wn + mi * 16 + lrow;
        bfr[ks][mi] = *(const bf16x8*)&Bt[rb * 64 + ((ks * 32 + lk8) ^ ((rb & 7) << 3))];
      }
#pragma unroll
    for (int ks = 0; ks < 2; ++ks)
#pragma unroll
      for (int mi = 0; mi < 4; ++mi)
#pragma unroll
        for (int ni = 0; ni < 4; ++ni)
          acc[mi][ni] = __builtin_amdgcn_mfma_f32_16x16x32_bf16(
              af[ks][mi], bfr[ks][ni], acc[mi][ni], 0, 0, 0);
  }

  const bool ropeq = do_rope && (blockIdx.z < 2);
  if (ropeq) {
    float frq[4];
#pragma unroll
    for (int ni = 0; ni < 4; ++ni)
      frq[ni] = exp2f((float)(((n0 + wn + ni * 16 + lrow) & 63) >> 1) *
                      -0.4152410118609203f);
#pragma unroll
    for (int mi = 0; mi < 4; ++mi)
#pragma unroll
      for (int r = 0; r < 4; ++r) {
        int row = m0 + wm + mi * 16 + (lane >> 4) * 4 + r;
        float ps = (float)pos[row & (SLEN - 1)];
#pragma unroll
        for (int ni = 0; ni < 4; ++ni) {
          float v = acc[mi][ni][r];
          float prt = __shfl_xor(v, 1);
          float sn, cs;
          __sincosf(ps * frq[ni], &sn, &cs);
          acc[mi][ni][r] = (lrow & 1) ? fmaf(prt, sn, v * cs)
                                      : fmaf(v, cs, -prt * sn);
        }
      }
  }

#pragma unroll
  for (int mi = 0; mi < 4; ++mi)
#pragma unroll
    for (int ni = 0; ni < 4; ++ni)
#pragma unroll
      for (int r = 0; r < 4; ++r) {
        int row = m0 + wm + mi * 16 + (lane >> 4) * 4 + r;
        int col = n0 + wn + ni * 16 + lrow;
        stv(Cp + (size_t)row * N + col, acc[mi][ni][r]);
      }
}

// ---------------- V transpose (per head) with PV virtual-k permutation -------
// VT[bh][d][S]: storage col S = tt*64 + s holds V[token = tt*64 + pi(s)][d]
// where pi(s) = (s&32) + 16*((s&7)>>2) + 4*((s>>3)&3) + (s&3). This makes each
// PV A-fragment a single contiguous 16B read in the attention kernel.
__global__ void transpose_v_kernel(const unsigned short* __restrict__ V,
                                   unsigned short* __restrict__ VT) {
  const int tt = blockIdx.x, bh = blockIdx.y;
  const int b = bh / NH, h = bh - b * NH;
  const unsigned short* src = V + ((size_t)b * SLEN + tt * 64) * DM + h * DKH;
  unsigned short* dst = VT + (size_t)bh * DKH * SLEN + tt * 64;
  __shared__ unsigned short lds[64][72];
  const int tid = threadIdx.x;
  const int r = tid >> 2, cq = tid & 3;
#pragma unroll
  for (int pass = 0; pass < 2; ++pass) {
    int c = cq * 8 + pass * 32;
    *(bf16x8*)&lds[r][c] = *(const bf16x8*)&src[(size_t)r * DM + c];
  }
  __syncthreads();
  const int d = tid >> 2;
#pragma unroll
  for (int pass = 0; pass < 2; ++pass) {
    int s0 = cq * 8 + pass * 32;
    union { unsigned short h[8]; bf16x8 v; } o;
#pragma unroll
    for (int j = 0; j < 8; ++j) {
      int pi = pass * 32 + 16 * (j >> 2) + 4 * cq + (j & 3);
      o.h[j] = lds[pi][d];
    }
    *(bf16x8*)&dst[(size_t)d * SLEN + s0] = o.v;
  }
}

// ---------------- causal flash attention: 4-wave LDS-shared ------------------
// QBLK=128 (wave w owns rows w*32..+31), KVBLK=64. K and VT tiles staged to
// LDS via global_load_lds (coalesced; 4x less L2 traffic than per-wave reg
// loads, 8x fewer cacheline txns), XOR-swizzled via pre-swizzled global source
// (both-sides rule). Double-buffered, one vmcnt(0)+barrier per tile (T3
// template order: stage(t+1) -> compute(t) -> bar). Swapped QK^T lane-local
// softmax + defer-max + cvt_pk P-pack kept from r7.
// NOTE (r6 lesson): do not tighten launch_bounds below 2 blocks of headroom.
__global__ __launch_bounds__(256, 2) void attn_kernel(
    const unsigned short* __restrict__ Q, const unsigned short* __restrict__ Kg,
    const unsigned short* __restrict__ VT, unsigned short* __restrict__ O) {
  const int bh = blockIdx.x;                 // 48 heads; %8 pins XCD
  const int qt = 15 - (int)blockIdx.y;       // heavy q-tiles dispatch first
  const int b = bh / NH, h = bh - b * NH;
  const size_t base = ((size_t)b * SLEN) * DM + h * DKH;
  const size_t vbase = (size_t)bh * DKH * SLEN;
  const int tid = threadIdx.x, wid = tid >> 6, lane = tid & 63;
  const int lrow = lane & 15, g = lane >> 4;

  __shared__ unsigned short Kt[2][64 * 64];  // [kr][d], swizzled
  __shared__ unsigned short Vt[2][64 * 64];  // [d][kv-perm], swizzled

  // Q fragments (B operand of swapped QK^T), scaled by 0.125*log2(e)
  bf16x8 qf[2][2];
#pragma unroll
  for (int mi = 0; mi < 2; ++mi)
#pragma unroll
    for (int ks = 0; ks < 2; ++ks) {
      const int qrow = qt * 128 + wid * 32 + mi * 16 + lrow;
      union { unsigned short h[8]; bf16x8 v; } u;
      u.v = *(const bf16x8*)&Q[base + (size_t)qrow * DM + ks * 32 + g * 8];
#pragma unroll
      for (int j = 0; j < 8; ++j)
        u.h[j] = f2b(b2f(u.h[j]) * 0.18033688011112042f);
      qf[mi][ks] = u.v;
    }

  f32x4 oacc[2][4] = {};
  float m_run[2] = {-1e30f, -1e30f};
  float l_part[2] = {0.f, 0.f};
  const int qg0 = qt * 128 + wid * 32 + lrow;
  const int nkt = 2 * qt + 2;

  const int srow = wid * 8 + (lane >> 3);    // staging row within 32-row round
  const int scol = (lane & 7) * 8;

  auto stage = [&](int kt, int buf) {
#pragma unroll
    for (int rnd = 0; rnd < 2; ++rnd) {
      int r = rnd * 32 + srow;
      int c = scol ^ ((r & 7) << 3);
      gld16(Kg + base + (size_t)(kt * 64 + r) * DM + c,
            &Kt[buf][(rnd * 32 + wid * 8) * 64]);
    }
#pragma unroll
    for (int rnd = 0; rnd < 2; ++rnd) {
      int d = rnd * 32 + srow;
      int c = scol ^ ((d & 7) << 3);
      gld16(VT + vbase + (size_t)d * SLEN + kt * 64 + c,
            &Vt[buf][(rnd * 32 + wid * 8) * 64]);
    }
  };

  auto compute = [&](int kt, int buf) {
    const bool active = !(kt == 2 * qt + 1 && wid < 2);
    if (!active) return;
    // S^T = K Q^T : sa[mi][ni][r] = S[q=mi*16+lrow][k=kt*64+ni*16+g*4+r] (log2)
    f32x4 sa[2][4] = {};
    const unsigned short* Ks = Kt[buf];
    __builtin_amdgcn_s_setprio(1);
#pragma unroll
    for (int ks = 0; ks < 2; ++ks)
#pragma unroll
      for (int ni = 0; ni < 4; ++ni) {
        const int krow = ni * 16 + lrow;
        bf16x8 kf = *(const bf16x8*)
            &Ks[krow * 64 + ((ks * 32 + g * 8) ^ ((krow & 7) << 3))];
#pragma unroll
        for (int mi = 0; mi < 2; ++mi)
          sa[mi][ni] = __builtin_amdgcn_mfma_f32_16x16x32_bf16(
              kf, qf[mi][ks], sa[mi][ni], 0, 0, 0);
      }
    __builtin_amdgcn_s_setprio(0);

    const bool need_mask = (kt * 64 + 64 > qt * 128 + wid * 32);
    if (need_mask) {
      const int kb = kt * 64 + g * 4;
#pragma unroll
      for (int mi = 0; mi < 2; ++mi) {
        const int qg = qg0 + mi * 16;
#pragma unroll
        for (int ni = 0; ni < 4; ++ni)
#pragma unroll
          for (int r = 0; r < 4; ++r)
            if (kb + ni * 16 + r > qg) sa[mi][ni][r] = -1e30f;
      }
    }

    // lane-local 16-element max
    float mx[2];
#pragma unroll
    for (int mi = 0; mi < 2; ++mi) {
      f32x4 t01, t23;
#pragma unroll
      for (int r = 0; r < 4; ++r) {
        t01[r] = fmaxf(sa[mi][0][r], sa[mi][1][r]);
        t23[r] = fmaxf(sa[mi][2][r], sa[mi][3][r]);
      }
      float a = fmaxf(fmaxf(t01[0], t23[0]), fmaxf(t01[1], t23[1]));
      float c = fmaxf(fmaxf(t01[2], t23[2]), fmaxf(t01[3], t23[3]));
      mx[mi] = fmaxf(a, c);
    }

    // defer-max: slow path only on violation
    const int viol = (mx[0] > m_run[0] + 8.f) || (mx[1] > m_run[1] + 8.f);
    if (__any(viol)) {
#pragma unroll
      for (int mi = 0; mi < 2; ++mi) {
        float mr = fmaxf(mx[mi], __shfl_xor(mx[mi], 16));
        mr = fmaxf(mr, __shfl_xor(mr, 32));
        float mn = fmaxf(m_run[mi], mr);
        float scl = exp2f(m_run[mi] - mn);
        m_run[mi] = mn;
        l_part[mi] *= scl;
#pragma unroll
        for (int ni = 0; ni < 4; ++ni) oacc[mi][ni] *= scl;
      }
    }

    // exp2 + per-lane l accumulation
#pragma unroll
    for (int mi = 0; mi < 2; ++mi) {
      float s0 = 0.f;
#pragma unroll
      for (int ni = 0; ni < 4; ++ni)
#pragma unroll
        for (int r = 0; r < 4; ++r) {
          float e = exp2f(sa[mi][ni][r] - m_run[mi]);
          sa[mi][ni][r] = e;
          s0 += e;
        }
      l_part[mi] += s0;
    }

    // pack P lane-local via cvt_pk (virtual kv = ks*32+g*8+j matches VT perm)
    bf16x8 pf[2][2];
#pragma unroll
    for (int mi = 0; mi < 2; ++mi)
#pragma unroll
      for (int ks = 0; ks < 2; ++ks) {
        union { unsigned u[4]; bf16x8 v; } uu;
        uu.u[0] = cvtpk(sa[mi][2 * ks][0],     sa[mi][2 * ks][1]);
        uu.u[1] = cvtpk(sa[mi][2 * ks][2],     sa[mi][2 * ks][3]);
        uu.u[2] = cvtpk(sa[mi][2 * ks + 1][0], sa[mi][2 * ks + 1][1]);
        uu.u[3] = cvtpk(sa[mi][2 * ks + 1][2], sa[mi][2 * ks + 1][3]);
        pf[mi][ks] = uu.v;
      }

    // O^T += V^T P^T  (A-frag: one swizzled b128 read from Vt)
    const unsigned short* Vs = Vt[buf];
    __builtin_amdgcn_s_setprio(1);
#pragma unroll
    for (int ks = 0; ks < 2; ++ks)
#pragma unroll
      for (int ni = 0; ni < 4; ++ni) {
        const int d = ni * 16 + lrow;
        bf16x8 vf = *(const bf16x8*)
            &Vs[d * 64 + ((ks * 32 + g * 8) ^ ((d & 7) << 3))];
#pragma unroll
        for (int mi = 0; mi < 2; ++mi)
          oacc[mi][ni] = __builtin_amdgcn_mfma_f32_16x16x32_bf16(
              vf, pf[mi][ks], oacc[mi][ni], 0, 0, 0);
      }
    __builtin_amdgcn_s_setprio(0);
  };

  stage(0, 0);
  TILE_BAR();
  for (int kt = 0; kt < nkt; ++kt) {
    const int cur = kt & 1;
    if (kt + 1 < nkt) stage(kt + 1, cur ^ 1);
    compute(kt, cur);
    TILE_BAR();
  }

  // epilogue: reduce l across the 4 lane-groups once; store O
#pragma unroll
  for (int mi = 0; mi < 2; ++mi) {
    float l = l_part[mi];
    l += __shfl_xor(l, 16);
    l += __shfl_xor(l, 32);
    const float inv = 1.f / l;
    const int qrow = qt * 128 + wid * 32 + mi * 16 + lrow;
#pragma unroll
    for (int ni = 0; ni < 4; ++ni) {
      union { unsigned u[2]; ushort4 s; } o;
      o.u[0] = cvtpk(oacc[mi][ni][0] * inv, oacc[mi][ni][1] * inv);
      o.u[1] = cvtpk(oacc[mi][ni][2] * inv, oacc[mi][ni][3] * inv);
      *(ushort4*)&O[base + (size_t)qrow * DM + ni * 16 + g * 4] = o.s;
    }
  }
}

// ---------------- launch ----------------
extern "C" void kernel_launch(void* const* d_in, const int* in_sizes, int n_in,
                              void* d_out, int out_size, void* d_ws, size_t ws_size,
                              hipStream_t stream) {
  const float* x  = (const float*)d_in[0];
  const float* Wq = (const float*)d_in[1];
  const float* Wk = (const float*)d_in[2];
  const float* Wv = (const float*)d_in[3];
  const float* Wo = (const float*)d_in[4];
  const int* pos  = (const int*)d_in[5];
  float* out = (float*)d_out;

  char* ws = (char*)d_ws;
  size_t off = 0;
  auto carve = [&](size_t bytes) -> void* {
    void* p = ws + off;
    off += (bytes + 255) & ~(size_t)255;
    return p;
  };
  unsigned short* xb  = (unsigned short*)carve((size_t)NTOK * DM * 2);
  unsigned short* wqb = (unsigned short*)carve((size_t)DM * DM * 2);
  unsigned short* wkb = (unsigned short*)carve((size_t)DM * DM * 2);
  unsigned short* wvb = (unsigned short*)carve((size_t)DM * DM * 2);
  unsigned short* wob = (unsigned short*)carve((size_t)DM * DM * 2);
  unsigned short* Qb  = (unsigned short*)carve((size_t)NTOK * DM * 2);
  unsigned short* Kb  = (unsigned short*)carve((size_t)NTOK * DM * 2);
  unsigned short* Vb  = (unsigned short*)carve((size_t)NTOK * DM * 2);
  unsigned short* Ab  = (unsigned short*)carve((size_t)NTOK * DM * 2);
  unsigned short* VTb = (unsigned short*)carve((size_t)4 * NH * DKH * SLEN * 2);

  const int n8x = NTOK * DM / 8;   // 786432
  const int n8w = DM * DM / 8;     // 73728
  cast_bf16_kernel<<<dim3((n8x + 255) / 256), dim3(256), 0, stream>>>(x, xb, n8x);
  cast_bf16_kernel<<<dim3((n8w + 255) / 256), dim3(256), 0, stream>>>(Wq, wqb, n8w);
  cast_bf16_kernel<<<dim3((n8w + 255) / 256), dim3(256), 0, stream>>>(Wk, wkb, n8w);
  cast_bf16_kernel<<<dim3((n8w + 255) / 256), dim3(256), 0, stream>>>(Wv, wvb, n8w);
  cast_bf16_kernel<<<dim3((n8w + 255) / 256), dim3(256), 0, stream>>>(Wo, wob, n8w);

  // fused QKV projection + RoPE-in-epilogue for Q,K (z<2)
  gemm_bt_kernel<unsigned short><<<dim3(6, 64, 3), dim3(256), 0, stream>>>(
      xb, wqb, wkb, wvb, Qb, Kb, Vb, DM, DM, pos, 1);

  transpose_v_kernel<<<dim3(SLEN / 64, 4 * NH), dim3(256), 0, stream>>>(Vb, VTb);

  attn_kernel<<<dim3(48, 16), dim3(256), 0, stream>>>(Qb, Kb, VTb, Ab);

  gemm_bt_kernel<float><<<dim3(6, 64, 1), dim3(256), 0, stream>>>(
      Ab, wob, wob, wob, out, out, out, DM, DM, pos, 0);
}